// Round 22
// baseline (276.660 us; speedup 1.0000x reference)
//
#include <hip/hip_runtime.h>

// Problem constants
#define NSAMP 262144
#define CCLS 128
#define DDIM 256
#define EPSF 1e-8f

// ws byte offsets
#define OFF_COUNTS 0u         // 128 * u32
#define OFF_SUMS   2048u      // 128x256 f32 sums (natural layout)
#define OFF_G      133120u    // 128x128 f32
#define OFF_W      198656u    // 128x128 f32 (G^-1)
#define OFF_TT     264192u    // 256x128 f32 (T transposed)
#define OFF_B      395264u    // 128x128 f32 (means @ T^T)
#define OFF_ZT     460800u    // 128x128 f32 (W @ B^T)
#define OFF_M      526336u    // 128x128 f32 (B W B^T)
#define OFF_BIG    1644288u   // slabs: 255 x 32768 f32 (128KB each)

// ---------------------------------------------------------------------------
// KA: 256 blocks x 1024 (grid EXACTLY 256 = 1 block/CU guaranteed residency).
//   Blocks 0..254 (~1028 samples each), ZERO LDS atomics (r19/r21-verified):
//     Phase 1: gated-only argmax via 16-lane groups, labels -> u8 LDS.
//     Phase 2: register-octet gather, ballot over labels, plain stores.
//   Block 255 (folded kg+GJ, both verified bodies, hidden under the ~155us
//   sample blocks; saves one serial launch):
//     (a) G = T*T^T (all 128 rows, 1024 thr: 64 row-pairs x 16 col-tiles)
//         + T^T, staged via Tl LDS tile;
//     (b) __syncthreads (same-block global writes visible per HIP semantics);
//     (c) Gauss-Jordan inversion of G -> W, 4x4 tile/thread (16 static regs,
//         cannot spill; r18/r21-verified).
// ---------------------------------------------------------------------------
extern "C" __global__ __launch_bounds__(1024)
void ka_fused(const float* __restrict__ logits, const float* __restrict__ img,
              const float* __restrict__ T, const void* __restrict__ mask,
              char* __restrict__ ws, int nSlab)
{
    __shared__ float Tl[64][132];                               // gram stage (block 255)
    __shared__ float prA[128], prB[128], pcA[128], pcB[128];    // GJ pivots
    __shared__ unsigned char labu[1088];                        // block labels
    __shared__ int sIsBool;
    const int b = blockIdx.x, tid = threadIdx.x;

    if (b == 255) {
        // ================= (a) Gram: G = T*T^T, all rows + T^T =============
        float* Tt = (float*)(ws + OFF_TT);
        float* G  = (float*)(ws + OFF_G);
        {
            float a0[8], a1[8];
            #pragma unroll
            for (int j = 0; j < 8; ++j) { a0[j] = 0.f; a1[j] = 0.f; }
            const int Lr = 2 * (tid >> 4);      // row pair 0..126 (64 pairs)
            const int c0 = 8 * (tid & 15);      // col tile
            for (int ch = 0; ch < 4; ++ch) {
                for (int i = tid; i < 8192; i += 1024) {
                    int cc = i >> 6, dd = i & 63;
                    Tl[dd][cc] = T[cc * 256 + ch * 64 + dd];
                }
                __syncthreads();
                // write T^T rows [64ch, 64ch+64)
                for (int i = tid; i < 8192; i += 1024) {
                    int c2 = i & 127, d2 = i >> 7;
                    Tt[(ch * 64 + d2) * 128 + c2] = Tl[d2][c2];
                }
                for (int dd = 0; dd < 64; ++dd) {
                    float r0 = Tl[dd][Lr];
                    float r1 = Tl[dd][Lr + 1];
                    float cv[8];
                    *(float4*)&cv[0] = *(const float4*)&Tl[dd][c0];
                    *(float4*)&cv[4] = *(const float4*)&Tl[dd][c0 + 4];
                    #pragma unroll
                    for (int j = 0; j < 8; ++j) { a0[j] += r0 * cv[j]; a1[j] += r1 * cv[j]; }
                }
                __syncthreads();
            }
            *(float4*)&G[Lr * 128 + c0]           = make_float4(a0[0], a0[1], a0[2], a0[3]);
            *(float4*)&G[Lr * 128 + c0 + 4]       = make_float4(a0[4], a0[5], a0[6], a0[7]);
            *(float4*)&G[(Lr + 1) * 128 + c0]     = make_float4(a1[0], a1[1], a1[2], a1[3]);
            *(float4*)&G[(Lr + 1) * 128 + c0 + 4] = make_float4(a1[4], a1[5], a1[6], a1[7]);
        }
        __syncthreads();   // G fully written & visible block-wide

        // ================= (c) Gauss-Jordan: W = G^-1 ======================
        float* W = (float*)(ws + OFF_W);
        float gg[4][4];
        const int r0 = 4 * (tid >> 5), c0 = 4 * (tid & 31);
        #pragma unroll
        for (int ii = 0; ii < 4; ++ii)
            *(float4*)&gg[ii][0] = *(const float4*)&G[(r0 + ii) * 128 + c0];
        if (r0 == 0) {
            #pragma unroll
            for (int j = 0; j < 4; ++j) prA[c0 + j] = gg[0][j];
        }
        if (c0 == 0) {
            #pragma unroll
            for (int i = 0; i < 4; ++i) pcA[r0 + i] = gg[i][0];
        }
        __syncthreads();
        for (int k = 0; k < 128; ++k) {
            const float* pr = (k & 1) ? prB : prA;
            const float* pc = (k & 1) ? pcB : pcA;
            float rinv = 1.0f / pr[k];
            float4 ra = *(const float4*)&pr[c0];
            float4 fa = *(const float4*)&pc[r0];
            float rf[4] = { ra.x, ra.y, ra.z, ra.w };
            float fcv[4] = { fa.x, fa.y, fa.z, fa.w };
            #pragma unroll
            for (int j = 0; j < 4; ++j) rf[j] = (c0 + j == k) ? rinv : rf[j] * rinv;
            #pragma unroll
            for (int i = 0; i < 4; ++i) {
                if (r0 + i == k) {
                    #pragma unroll
                    for (int j = 0; j < 4; ++j) gg[i][j] = rf[j];
                } else {
                    float f = fcv[i];
                    #pragma unroll
                    for (int j = 0; j < 4; ++j) {
                        float base = (c0 + j == k) ? 0.0f : gg[i][j];
                        gg[i][j] = base - f * rf[j];
                    }
                }
            }
            const int kn = k + 1;
            if (kn < 128) {
                float* prn = (kn & 1) ? prB : prA;
                float* pcn = (kn & 1) ? pcB : pcA;
                #pragma unroll
                for (int ii = 0; ii < 4; ++ii) {
                    if (r0 + ii == kn) {
                        #pragma unroll
                        for (int j = 0; j < 4; ++j) prn[c0 + j] = gg[ii][j];
                    }
                }
                #pragma unroll
                for (int jj = 0; jj < 4; ++jj) {
                    if (c0 + jj == kn) {
                        #pragma unroll
                        for (int i = 0; i < 4; ++i) pcn[r0 + i] = gg[i][jj];
                    }
                }
            }
            __syncthreads();
        }
        #pragma unroll
        for (int ii = 0; ii < 4; ++ii)
            *(float4*)&W[(r0 + ii) * 128 + c0] = *(float4*)&gg[ii][0];
        return;
    }

    // ---- sample blocks: range [b*1028, end) ----
    const int start = b * 1028;
    const int end = (b == 254) ? NSAMP : start + 1028;
    const int nS = end - start;
    {
        for (int i = tid; i < 1088; i += 1024) labu[i] = 255;
        int v = 0;
        if (tid < 64) v = ((const int*)mask)[tid];
        unsigned long long bal = __ballot((unsigned)v > 1u);
        if (tid == 0) sIsBool = (bal != 0ull);
    }
    __syncthreads();
    const bool isBool = (sIsBool != 0);

    const int wave = tid >> 6, lane = tid & 63;
    const int sg = lane >> 4, l16 = lane & 15;
    const float4* lp4 = (const float4*)logits;   // 32 float4 per row
    const float4* im4 = (const float4*)img;      // 64 float4 per row

    // ================= Phase 1: gated argmax -> labels (LDS) ===============
    for (int off = wave * 64; off < nS; off += 1024) {
        const int sw = start + off;
        int gv = 0;
        if (off + lane < nS)
            gv = isBool ? (int)((const unsigned char*)mask)[sw + lane]
                        : ((const int*)mask)[sw + lane];
        unsigned long long gm = __ballot(gv != 0);

        while (gm) {
            int b0 = 0, b1 = 0, b2 = 0, b3 = 0, cn = 0;
            {
                unsigned long long t = gm;
                if (t) { b0 = (int)(__ffsll((long long)t) - 1); t &= t - 1; ++cn; }
                if (t) { b1 = (int)(__ffsll((long long)t) - 1); t &= t - 1; ++cn; }
                if (t) { b2 = (int)(__ffsll((long long)t) - 1); t &= t - 1; ++cn; }
                if (t) { b3 = (int)(__ffsll((long long)t) - 1); t &= t - 1; ++cn; }
                gm = t;
            }
            const int myb = (sg == 0) ? b0 : (sg == 1) ? b1 : (sg == 2) ? b2 : b3;
            const bool act = (sg < cn);
            const int srow = sw + myb;
            float4 A = lp4[(size_t)srow * 32 + l16];
            float4 B4 = lp4[(size_t)srow * 32 + 16 + l16];
            float m = A.x; int id = 4 * l16;
            if (A.y > m) { m = A.y; id = 4 * l16 + 1; }
            if (A.z > m) { m = A.z; id = 4 * l16 + 2; }
            if (A.w > m) { m = A.w; id = 4 * l16 + 3; }
            if (B4.x > m) { m = B4.x; id = 64 + 4 * l16; }
            if (B4.y > m) { m = B4.y; id = 64 + 4 * l16 + 1; }
            if (B4.z > m) { m = B4.z; id = 64 + 4 * l16 + 2; }
            if (B4.w > m) { m = B4.w; id = 64 + 4 * l16 + 3; }
            #pragma unroll
            for (int o = 1; o < 16; o <<= 1) {
                float om = __shfl_xor(m, o);
                int   oi = __shfl_xor(id, o);
                if (om > m || (om == m && oi < id)) { m = om; id = oi; }
            }
            if (l16 == 0 && act) labu[off + myb] = (unsigned char)id;
        }
    }
    __syncthreads();

    // ================= Phase 2: register-octet gather =======================
    float4 acc[8]; int cnt[8];
    #pragma unroll
    for (int c = 0; c < 8; ++c) { acc[c] = make_float4(0.f, 0.f, 0.f, 0.f); cnt[c] = 0; }

    const int nCh = (nS + 63) >> 6;
    for (int ch = 0; ch < nCh; ++ch) {
        int lab = labu[ch * 64 + lane];                     // 255 pads excluded
        unsigned long long mb = __ballot((lab >> 3) == wave);
        while (mb) {
            int bit = (int)(__ffsll((long long)mb) - 1); mb &= mb - 1;
            int lc = __shfl(lab, bit) & 7;
            float4 v = im4[(size_t)(start + ch * 64 + bit) * 64 + lane];
            #pragma unroll
            for (int c = 0; c < 8; ++c) {
                bool p = (lc == c);
                acc[c].x += p ? v.x : 0.f; acc[c].y += p ? v.y : 0.f;
                acc[c].z += p ? v.z : 0.f; acc[c].w += p ? v.w : 0.f;
                cnt[c]   += p ? 1 : 0;
            }
        }
    }

    // flush: natural [class][dim] layout, plain stores
    if (nSlab >= 255) {
        float* slab = (float*)(ws + OFF_BIG) + (size_t)b * 32768;
        #pragma unroll
        for (int c = 0; c < 8; ++c)
            *(float4*)&slab[(wave * 8 + c) * 256 + 4 * lane] = acc[c];
    } else {
        float* slab = (float*)(ws + OFF_BIG) + (size_t)(b % nSlab) * 32768;
        #pragma unroll
        for (int c = 0; c < 8; ++c) {
            unsafeAtomicAdd(&slab[(wave * 8 + c) * 256 + 4 * lane],     acc[c].x);
            unsafeAtomicAdd(&slab[(wave * 8 + c) * 256 + 4 * lane + 1], acc[c].y);
            unsafeAtomicAdd(&slab[(wave * 8 + c) * 256 + 4 * lane + 2], acc[c].z);
            unsafeAtomicAdd(&slab[(wave * 8 + c) * 256 + 4 * lane + 3], acc[c].w);
        }
    }
    if (lane == 0) {
        int* counts = (int*)(ws + OFF_COUNTS);
        #pragma unroll
        for (int c = 0; c < 8; ++c)
            if (cnt[c]) atomicAdd(&counts[wave * 8 + c], cnt[c]);
    }
}

// ---------------------------------------------------------------------------
// KR: deterministic slab reduction -> sums (natural). 256 blocks x 1024 thr.
//     (r21-verified: 8-way slab-parallel + LDS combine, 16 waves/CU)
// ---------------------------------------------------------------------------
extern "C" __global__ __launch_bounds__(1024)
void kr_sums(char* __restrict__ ws, int nRed)
{
    __shared__ float part[8][128];
    const int tid = threadIdx.x;
    const int p = tid >> 7, j = tid & 127;
    const int idx = blockIdx.x * 128 + j;        // [0, 32768)
    const float* base = (const float*)(ws + OFF_BIG) + idx;
    float a = 0.f;
    for (int r = p; r < nRed; r += 8) a += base[(size_t)r * 32768];
    part[p][j] = a;
    __syncthreads();
    if (tid < 128) {
        float s = part[0][tid] + part[1][tid] + part[2][tid] + part[3][tid]
                + part[4][tid] + part[5][tid] + part[6][tid] + part[7][tid];
        ((float*)(ws + OFF_SUMS))[idx] = s;
    }
}

// K4: B = (sums/counts) @ T^T  (mean-divide fused; natural layout)
extern "C" __global__ __launch_bounds__(128)
void k4_B(char* __restrict__ ws)
{
    __shared__ float mr[256];
    const int c = blockIdx.x, j = threadIdx.x;
    const float* sums = (const float*)(ws + OFF_SUMS);
    const int* counts = (const int*)(ws + OFF_COUNTS);
    const float* Tt = (const float*)(ws + OFF_TT);
    float rcp = 1.0f / fmaxf((float)counts[c], 1.0f);
    mr[j] = sums[c * 256 + j] * rcp;
    mr[j + 128] = sums[c * 256 + 128 + j] * rcp;
    __syncthreads();
    float a = 0.f;
    #pragma unroll 8
    for (int d = 0; d < 256; ++d) a += mr[d] * Tt[d * 128 + j];
    ((float*)(ws + OFF_B))[c * 128 + j] = a;
}

// K5: Zt = (B @ W)^T = W @ B^T   (W symmetric)
extern "C" __global__ __launch_bounds__(128)
void k5_Z(char* __restrict__ ws)
{
    __shared__ float bc[128];
    const int c = blockIdx.x, j = threadIdx.x;
    const float* B = (const float*)(ws + OFF_B);
    const float* W = (const float*)(ws + OFF_W);
    bc[j] = B[c * 128 + j];
    __syncthreads();
    float a = 0.f;
    #pragma unroll 8
    for (int k = 0; k < 128; ++k) a += bc[k] * W[k * 128 + j];
    ((float*)(ws + OFF_ZT))[j * 128 + c] = a;
}

// K6: M = B @ Zt = B W B^T
extern "C" __global__ __launch_bounds__(128)
void k6_M(char* __restrict__ ws)
{
    __shared__ float bc[128];
    const int c = blockIdx.x, j = threadIdx.x;
    const float* B = (const float*)(ws + OFF_B);
    const float* Zt = (const float*)(ws + OFF_ZT);
    bc[j] = B[c * 128 + j];
    __syncthreads();
    float a = 0.f;
    #pragma unroll 8
    for (int k = 0; k < 128; ++k) a += bc[k] * Zt[k * 128 + j];
    ((float*)(ws + OFF_M))[c * 128 + j] = a;
}

// K7: loss
extern "C" __global__ __launch_bounds__(256)
void k7_loss(char* __restrict__ ws, float* __restrict__ out)
{
    __shared__ float norms[128];
    __shared__ int pres[128];
    __shared__ float wsum[4];
    const int tid = threadIdx.x;
    const float* M = (const float*)(ws + OFF_M);
    const int* counts = (const int*)(ws + OFF_COUNTS);
    if (tid < 128) {
        int p = counts[tid] > 0;
        pres[tid] = p;
        norms[tid] = sqrtf(p ? M[tid * 129] : 1.0f);
    }
    __syncthreads();
    float ls = 0.f;
    for (int idx = tid; idx < 16384; idx += 256) {
        int c = idx >> 7, j = idx & 127;
        if (c != j && pres[c] && pres[j])
            ls += 1.0f - M[idx] / ((norms[c] + EPSF) * (norms[j] + EPSF));
    }
    #pragma unroll
    for (int off = 32; off > 0; off >>= 1) ls += __shfl_down(ls, off);
    if ((tid & 63) == 0) wsum[tid >> 6] = ls;
    __syncthreads();
    if (tid == 0) {
        int np = 0;
        for (int c = 0; c < 128; ++c) np += pres[c];
        float tot = wsum[0] + wsum[1] + wsum[2] + wsum[3];
        out[0] = (np >= 2) ? tot : 0.0f;
    }
}

// ---------------------------------------------------------------------------
extern "C" void kernel_launch(void* const* d_in, const int* in_sizes, int n_in,
                              void* d_out, int out_size, void* d_ws, size_t ws_size,
                              hipStream_t stream)
{
    const float* logits = (const float*)d_in[0];
    const float* img    = (const float*)d_in[1];
    const float* T      = (const float*)d_in[2];
    const void*  mask   = d_in[3];
    char* ws = (char*)d_ws;

    size_t avail = (ws_size > (size_t)OFF_BIG) ? ws_size - OFF_BIG : 0;
    int nSlab = (int)(avail / 131072);   // 128 KB per slab
    if (nSlab > 255) nSlab = 255;
    if (nSlab < 1) nSlab = 1;

    hipMemsetAsync(ws + OFF_COUNTS, 0, 512, stream);
    if (nSlab < 255)
        hipMemsetAsync(ws + OFF_BIG, 0, (size_t)nSlab * 131072, stream);

    ka_fused<<<256, 1024, 0, stream>>>(logits, img, T, mask, ws, nSlab); // 2-phase + gram/GJ
    kr_sums<<<256, 1024, 0, stream>>>(ws, nSlab);                // slab reduce -> sums
    k4_B<<<128, 128, 0, stream>>>(ws);
    k5_Z<<<128, 128, 0, stream>>>(ws);
    k6_M<<<128, 128, 0, stream>>>(ws);
    k7_loss<<<1, 256, 0, stream>>>(ws, (float*)d_out);
}

// Round 23
// 209.887 us; speedup vs baseline: 1.3181x; 1.3181x over previous
//
#include <hip/hip_runtime.h>

// Problem constants
#define NSAMP 262144
#define CCLS 128
#define DDIM 256
#define EPSF 1e-8f

// ws byte offsets
#define OFF_COUNTS 0u         // 128 * u32
#define OFF_SUMS   2048u      // 128x256 f32 sums (natural layout)
#define OFF_G      133120u    // 128x128 f32
#define OFF_W      198656u    // 128x128 f32 (G^-1)
#define OFF_TT     264192u    // 256x128 f32 (T transposed)
#define OFF_B      395264u    // 128x128 f32 (means @ T^T)
#define OFF_ZT     460800u    // 128x128 f32 (W @ B^T)
#define OFF_M      526336u    // 128x128 f32 (B W B^T)
#define OFF_BIG    1644288u   // slabs: 255 x 32768 f32 (128KB each)

// ---------------------------------------------------------------------------
// KG: 4 blocks x 1024. Block g computes rows [32g,32g+32) of G = T*T^T and
//     writes T^T chunk g. (verbatim verified; kept SEPARATE — r22 proved
//     folding it into ka taxes every block with its 34KB LDS tile: 155->212us)
// ---------------------------------------------------------------------------
extern "C" __global__ __launch_bounds__(1024)
void kg_gram(const float* __restrict__ T, char* __restrict__ ws)
{
    __shared__ float Tl[64][132];
    const int g = blockIdx.x, tid = threadIdx.x;
    float* Tt = (float*)(ws + OFF_TT);
    float* G  = (float*)(ws + OFF_G);
    float a0[8], a1[8];
    #pragma unroll
    for (int j = 0; j < 8; ++j) { a0[j] = 0.f; a1[j] = 0.f; }
    const int Lr = 2 * (tid >> 4);
    const int c0 = 8 * (tid & 15);
    for (int ch = 0; ch < 4; ++ch) {
        for (int i = tid; i < 8192; i += 1024) {
            int cc = i >> 6, dd = i & 63;
            Tl[dd][cc] = T[cc * 256 + ch * 64 + dd];
        }
        __syncthreads();
        if (g == ch) {
            for (int i = tid; i < 8192; i += 1024) {
                int c2 = i & 127, d2 = i >> 7;
                Tt[(ch * 64 + d2) * 128 + c2] = Tl[d2][c2];
            }
        }
        if (tid < 256) {
            for (int dd = 0; dd < 64; ++dd) {
                float r0 = Tl[dd][32 * g + Lr];
                float r1 = Tl[dd][32 * g + Lr + 1];
                float cv[8];
                *(float4*)&cv[0] = *(const float4*)&Tl[dd][c0];
                *(float4*)&cv[4] = *(const float4*)&Tl[dd][c0 + 4];
                #pragma unroll
                for (int j = 0; j < 8; ++j) { a0[j] += r0 * cv[j]; a1[j] += r1 * cv[j]; }
            }
        }
        __syncthreads();
    }
    if (tid < 256) {
        int gr = 32 * g + Lr;
        *(float4*)&G[gr * 128 + c0]           = make_float4(a0[0], a0[1], a0[2], a0[3]);
        *(float4*)&G[gr * 128 + c0 + 4]       = make_float4(a0[4], a0[5], a0[6], a0[7]);
        *(float4*)&G[(gr + 1) * 128 + c0]     = make_float4(a1[0], a1[1], a1[2], a1[3]);
        *(float4*)&G[(gr + 1) * 128 + c0 + 4] = make_float4(a1[4], a1[5], a1[6], a1[7]);
    }
}

// ---------------------------------------------------------------------------
// KA: 256 blocks x 1024 (grid EXACTLY 256 = 1 block/CU guaranteed residency;
//     r20 proved grid 512 = exact machine capacity is fragile -> GJ tail).
//   Blocks 0..254 (~1028 samples each), ZERO LDS atomics (r19/r21-verified):
//     Phase 1: gated-only argmax via 16-lane groups, labels -> u8 LDS.
//     Phase 2: register-octet gather, ballot over labels, plain stores.
//   Block 255: Gauss-Jordan inversion of G -> W (4x4/1024thr, r18-verified).
// ---------------------------------------------------------------------------
extern "C" __global__ __launch_bounds__(1024)
void ka_fused(const float* __restrict__ logits, const float* __restrict__ img,
              const void* __restrict__ mask, char* __restrict__ ws, int nSlab)
{
    __shared__ float prA[128], prB[128], pcA[128], pcB[128];   // GJ pivots
    __shared__ unsigned char labu[1088];                        // block labels
    __shared__ int sIsBool;
    const int b = blockIdx.x, tid = threadIdx.x;

    if (b == 255) {
        // ---- Gauss-Jordan inversion, 1024 threads, 4x4 tiles ----
        const float* G = (const float*)(ws + OFF_G);
        float* W = (float*)(ws + OFF_W);
        float gg[4][4];
        const int r0 = 4 * (tid >> 5), c0 = 4 * (tid & 31);
        #pragma unroll
        for (int ii = 0; ii < 4; ++ii)
            *(float4*)&gg[ii][0] = *(const float4*)&G[(r0 + ii) * 128 + c0];
        if (r0 == 0) {
            #pragma unroll
            for (int j = 0; j < 4; ++j) prA[c0 + j] = gg[0][j];
        }
        if (c0 == 0) {
            #pragma unroll
            for (int i = 0; i < 4; ++i) pcA[r0 + i] = gg[i][0];
        }
        __syncthreads();
        for (int k = 0; k < 128; ++k) {
            const float* pr = (k & 1) ? prB : prA;
            const float* pc = (k & 1) ? pcB : pcA;
            float rinv = 1.0f / pr[k];
            float4 ra = *(const float4*)&pr[c0];
            float4 fa = *(const float4*)&pc[r0];
            float rf[4] = { ra.x, ra.y, ra.z, ra.w };
            float fcv[4] = { fa.x, fa.y, fa.z, fa.w };
            #pragma unroll
            for (int j = 0; j < 4; ++j) rf[j] = (c0 + j == k) ? rinv : rf[j] * rinv;
            #pragma unroll
            for (int i = 0; i < 4; ++i) {
                if (r0 + i == k) {
                    #pragma unroll
                    for (int j = 0; j < 4; ++j) gg[i][j] = rf[j];
                } else {
                    float f = fcv[i];
                    #pragma unroll
                    for (int j = 0; j < 4; ++j) {
                        float base = (c0 + j == k) ? 0.0f : gg[i][j];
                        gg[i][j] = base - f * rf[j];
                    }
                }
            }
            const int kn = k + 1;
            if (kn < 128) {
                float* prn = (kn & 1) ? prB : prA;
                float* pcn = (kn & 1) ? pcB : pcA;
                #pragma unroll
                for (int ii = 0; ii < 4; ++ii) {
                    if (r0 + ii == kn) {
                        #pragma unroll
                        for (int j = 0; j < 4; ++j) prn[c0 + j] = gg[ii][j];
                    }
                }
                #pragma unroll
                for (int jj = 0; jj < 4; ++jj) {
                    if (c0 + jj == kn) {
                        #pragma unroll
                        for (int i = 0; i < 4; ++i) pcn[r0 + i] = gg[i][jj];
                    }
                }
            }
            __syncthreads();
        }
        #pragma unroll
        for (int ii = 0; ii < 4; ++ii)
            *(float4*)&W[(r0 + ii) * 128 + c0] = *(float4*)&gg[ii][0];
        return;
    }

    // ---- sample blocks: range [b*1028, end) ----
    const int start = b * 1028;
    const int end = (b == 254) ? NSAMP : start + 1028;
    const int nS = end - start;
    {
        for (int i = tid; i < 1088; i += 1024) labu[i] = 255;
        int v = 0;
        if (tid < 64) v = ((const int*)mask)[tid];
        unsigned long long bal = __ballot((unsigned)v > 1u);
        if (tid == 0) sIsBool = (bal != 0ull);
    }
    __syncthreads();
    const bool isBool = (sIsBool != 0);

    const int wave = tid >> 6, lane = tid & 63;
    const int sg = lane >> 4, l16 = lane & 15;
    const float4* lp4 = (const float4*)logits;   // 32 float4 per row
    const float4* im4 = (const float4*)img;      // 64 float4 per row

    // ================= Phase 1: gated argmax -> labels (LDS) ===============
    for (int off = wave * 64; off < nS; off += 1024) {
        const int sw = start + off;
        int gv = 0;
        if (off + lane < nS)
            gv = isBool ? (int)((const unsigned char*)mask)[sw + lane]
                        : ((const int*)mask)[sw + lane];
        unsigned long long gm = __ballot(gv != 0);

        while (gm) {
            int b0 = 0, b1 = 0, b2 = 0, b3 = 0, cn = 0;
            {
                unsigned long long t = gm;
                if (t) { b0 = (int)(__ffsll((long long)t) - 1); t &= t - 1; ++cn; }
                if (t) { b1 = (int)(__ffsll((long long)t) - 1); t &= t - 1; ++cn; }
                if (t) { b2 = (int)(__ffsll((long long)t) - 1); t &= t - 1; ++cn; }
                if (t) { b3 = (int)(__ffsll((long long)t) - 1); t &= t - 1; ++cn; }
                gm = t;
            }
            const int myb = (sg == 0) ? b0 : (sg == 1) ? b1 : (sg == 2) ? b2 : b3;
            const bool act = (sg < cn);
            const int srow = sw + myb;
            float4 A = lp4[(size_t)srow * 32 + l16];
            float4 B4 = lp4[(size_t)srow * 32 + 16 + l16];
            float m = A.x; int id = 4 * l16;
            if (A.y > m) { m = A.y; id = 4 * l16 + 1; }
            if (A.z > m) { m = A.z; id = 4 * l16 + 2; }
            if (A.w > m) { m = A.w; id = 4 * l16 + 3; }
            if (B4.x > m) { m = B4.x; id = 64 + 4 * l16; }
            if (B4.y > m) { m = B4.y; id = 64 + 4 * l16 + 1; }
            if (B4.z > m) { m = B4.z; id = 64 + 4 * l16 + 2; }
            if (B4.w > m) { m = B4.w; id = 64 + 4 * l16 + 3; }
            #pragma unroll
            for (int o = 1; o < 16; o <<= 1) {
                float om = __shfl_xor(m, o);
                int   oi = __shfl_xor(id, o);
                if (om > m || (om == m && oi < id)) { m = om; id = oi; }
            }
            if (l16 == 0 && act) labu[off + myb] = (unsigned char)id;
        }
    }
    __syncthreads();

    // ================= Phase 2: register-octet gather =======================
    float4 acc[8]; int cnt[8];
    #pragma unroll
    for (int c = 0; c < 8; ++c) { acc[c] = make_float4(0.f, 0.f, 0.f, 0.f); cnt[c] = 0; }

    const int nCh = (nS + 63) >> 6;
    for (int ch = 0; ch < nCh; ++ch) {
        int lab = labu[ch * 64 + lane];                     // 255 pads excluded
        unsigned long long mb = __ballot((lab >> 3) == wave);
        while (mb) {
            int bit = (int)(__ffsll((long long)mb) - 1); mb &= mb - 1;
            int lc = __shfl(lab, bit) & 7;
            float4 v = im4[(size_t)(start + ch * 64 + bit) * 64 + lane];
            #pragma unroll
            for (int c = 0; c < 8; ++c) {
                bool p = (lc == c);
                acc[c].x += p ? v.x : 0.f; acc[c].y += p ? v.y : 0.f;
                acc[c].z += p ? v.z : 0.f; acc[c].w += p ? v.w : 0.f;
                cnt[c]   += p ? 1 : 0;
            }
        }
    }

    // flush: natural [class][dim] layout, plain stores
    if (nSlab >= 255) {
        float* slab = (float*)(ws + OFF_BIG) + (size_t)b * 32768;
        #pragma unroll
        for (int c = 0; c < 8; ++c)
            *(float4*)&slab[(wave * 8 + c) * 256 + 4 * lane] = acc[c];
    } else {
        float* slab = (float*)(ws + OFF_BIG) + (size_t)(b % nSlab) * 32768;
        #pragma unroll
        for (int c = 0; c < 8; ++c) {
            unsafeAtomicAdd(&slab[(wave * 8 + c) * 256 + 4 * lane],     acc[c].x);
            unsafeAtomicAdd(&slab[(wave * 8 + c) * 256 + 4 * lane + 1], acc[c].y);
            unsafeAtomicAdd(&slab[(wave * 8 + c) * 256 + 4 * lane + 2], acc[c].z);
            unsafeAtomicAdd(&slab[(wave * 8 + c) * 256 + 4 * lane + 3], acc[c].w);
        }
    }
    if (lane == 0) {
        int* counts = (int*)(ws + OFF_COUNTS);
        #pragma unroll
        for (int c = 0; c < 8; ++c)
            if (cnt[c]) atomicAdd(&counts[wave * 8 + c], cnt[c]);
    }
}

// ---------------------------------------------------------------------------
// KR: deterministic slab reduction -> sums (natural). 256 blocks x 1024 thr.
//     (r21-verified: 8-way slab-parallel + LDS combine, 16 waves/CU)
// ---------------------------------------------------------------------------
extern "C" __global__ __launch_bounds__(1024)
void kr_sums(char* __restrict__ ws, int nRed)
{
    __shared__ float part[8][128];
    const int tid = threadIdx.x;
    const int p = tid >> 7, j = tid & 127;
    const int idx = blockIdx.x * 128 + j;        // [0, 32768)
    const float* base = (const float*)(ws + OFF_BIG) + idx;
    float a = 0.f;
    for (int r = p; r < nRed; r += 8) a += base[(size_t)r * 32768];
    part[p][j] = a;
    __syncthreads();
    if (tid < 128) {
        float s = part[0][tid] + part[1][tid] + part[2][tid] + part[3][tid]
                + part[4][tid] + part[5][tid] + part[6][tid] + part[7][tid];
        ((float*)(ws + OFF_SUMS))[idx] = s;
    }
}

// K4: B = (sums/counts) @ T^T  (mean-divide fused; natural layout)
extern "C" __global__ __launch_bounds__(128)
void k4_B(char* __restrict__ ws)
{
    __shared__ float mr[256];
    const int c = blockIdx.x, j = threadIdx.x;
    const float* sums = (const float*)(ws + OFF_SUMS);
    const int* counts = (const int*)(ws + OFF_COUNTS);
    const float* Tt = (const float*)(ws + OFF_TT);
    float rcp = 1.0f / fmaxf((float)counts[c], 1.0f);
    mr[j] = sums[c * 256 + j] * rcp;
    mr[j + 128] = sums[c * 256 + 128 + j] * rcp;
    __syncthreads();
    float a = 0.f;
    #pragma unroll 8
    for (int d = 0; d < 256; ++d) a += mr[d] * Tt[d * 128 + j];
    ((float*)(ws + OFF_B))[c * 128 + j] = a;
}

// K5: Zt = (B @ W)^T = W @ B^T   (W symmetric)
extern "C" __global__ __launch_bounds__(128)
void k5_Z(char* __restrict__ ws)
{
    __shared__ float bc[128];
    const int c = blockIdx.x, j = threadIdx.x;
    const float* B = (const float*)(ws + OFF_B);
    const float* W = (const float*)(ws + OFF_W);
    bc[j] = B[c * 128 + j];
    __syncthreads();
    float a = 0.f;
    #pragma unroll 8
    for (int k = 0; k < 128; ++k) a += bc[k] * W[k * 128 + j];
    ((float*)(ws + OFF_ZT))[j * 128 + c] = a;
}

// K6: M = B @ Zt = B W B^T
extern "C" __global__ __launch_bounds__(128)
void k6_M(char* __restrict__ ws)
{
    __shared__ float bc[128];
    const int c = blockIdx.x, j = threadIdx.x;
    const float* B = (const float*)(ws + OFF_B);
    const float* Zt = (const float*)(ws + OFF_ZT);
    bc[j] = B[c * 128 + j];
    __syncthreads();
    float a = 0.f;
    #pragma unroll 8
    for (int k = 0; k < 128; ++k) a += bc[k] * Zt[k * 128 + j];
    ((float*)(ws + OFF_M))[c * 128 + j] = a;
}

// K7: loss
extern "C" __global__ __launch_bounds__(256)
void k7_loss(char* __restrict__ ws, float* __restrict__ out)
{
    __shared__ float norms[128];
    __shared__ int pres[128];
    __shared__ float wsum[4];
    const int tid = threadIdx.x;
    const float* M = (const float*)(ws + OFF_M);
    const int* counts = (const int*)(ws + OFF_COUNTS);
    if (tid < 128) {
        int p = counts[tid] > 0;
        pres[tid] = p;
        norms[tid] = sqrtf(p ? M[tid * 129] : 1.0f);
    }
    __syncthreads();
    float ls = 0.f;
    for (int idx = tid; idx < 16384; idx += 256) {
        int c = idx >> 7, j = idx & 127;
        if (c != j && pres[c] && pres[j])
            ls += 1.0f - M[idx] / ((norms[c] + EPSF) * (norms[j] + EPSF));
    }
    #pragma unroll
    for (int off = 32; off > 0; off >>= 1) ls += __shfl_down(ls, off);
    if ((tid & 63) == 0) wsum[tid >> 6] = ls;
    __syncthreads();
    if (tid == 0) {
        int np = 0;
        for (int c = 0; c < 128; ++c) np += pres[c];
        float tot = wsum[0] + wsum[1] + wsum[2] + wsum[3];
        out[0] = (np >= 2) ? tot : 0.0f;
    }
}

// ---------------------------------------------------------------------------
extern "C" void kernel_launch(void* const* d_in, const int* in_sizes, int n_in,
                              void* d_out, int out_size, void* d_ws, size_t ws_size,
                              hipStream_t stream)
{
    const float* logits = (const float*)d_in[0];
    const float* img    = (const float*)d_in[1];
    const float* T      = (const float*)d_in[2];
    const void*  mask   = d_in[3];
    char* ws = (char*)d_ws;

    size_t avail = (ws_size > (size_t)OFF_BIG) ? ws_size - OFF_BIG : 0;
    int nSlab = (int)(avail / 131072);   // 128 KB per slab
    if (nSlab > 255) nSlab = 255;
    if (nSlab < 1) nSlab = 1;

    hipMemsetAsync(ws + OFF_COUNTS, 0, 512, stream);
    if (nSlab < 255)
        hipMemsetAsync(ws + OFF_BIG, 0, (size_t)nSlab * 131072, stream);

    kg_gram<<<4, 1024, 0, stream>>>(T, ws);                      // G + T^T
    ka_fused<<<256, 1024, 0, stream>>>(logits, img, mask, ws, nSlab); // 2-phase + GJ
    kr_sums<<<256, 1024, 0, stream>>>(ws, nSlab);                // slab reduce -> sums
    k4_B<<<128, 128, 0, stream>>>(ws);
    k5_Z<<<128, 128, 0, stream>>>(ws);
    k6_M<<<128, 128, 0, stream>>>(ws);
    k7_loss<<<1, 256, 0, stream>>>(ws, (float*)d_out);
}